// Round 8
// baseline (245.865 us; speedup 1.0000x reference)
//
#include <hip/hip_runtime.h>
#include <math.h>

#define NB 4096
#define KN 64
#define DIM 128
#define HP 132   // LDS pitch (bf16): 264B/row

typedef __bf16 bf16;
typedef bf16 bf16x8 __attribute__((ext_vector_type(8)));
typedef bf16 bf16x4 __attribute__((ext_vector_type(4)));
typedef float f32x4 __attribute__((ext_vector_type(4)));

// w1T[j][i] = w1[i][j]  (128 x 256 bf16), w2T[j2][j1] = w2[j1][j2] (128 x 128)
__global__ void prep_weights(const float* __restrict__ w1,
                             const float* __restrict__ w2,
                             bf16* __restrict__ w1T,
                             bf16* __restrict__ w2T) {
    int t = blockIdx.x * 256 + threadIdx.x;
    if (t < 128 * 256) {
        int j = t >> 8, i = t & 255;
        w1T[t] = (bf16)w1[i * 128 + j];
    } else {
        int t2 = t - 128 * 256;
        int j2 = t2 >> 7, j1 = t2 & 127;
        w2T[t2] = (bf16)w2[j1 * 128 + j2];
    }
}

// one block per (b, modality); one WAVE per 16-neighbor k-tile, end-to-end
__global__ __launch_bounds__(256, 4) void graphsage_mfma(
    const int* __restrict__ node_idx,
    const int* __restrict__ neigh_idx,
    const int* __restrict__ neigh_len,
    const float* __restrict__ emb_v,
    const float* __restrict__ emb_t,
    const bf16* __restrict__ w1T,
    const float* __restrict__ b1,
    const bf16* __restrict__ w2T,
    const float* __restrict__ b2,
    const float* __restrict__ w3,
    float* __restrict__ out)
{
    __shared__ bf16  n_lds[KN][HP];      // 16896 B  (wave-private 16-row slices)
    __shared__ bf16  h1_lds[KN][HP];     // 16896 B  (wave-private 16-row slices)
    __shared__ float u_lds[DIM];         // 512 B
    __shared__ float part_lds[2][DIM];   // 1024 B (uq halves)
    __shared__ float s_lds[KN];          // 256 B
    __shared__ float scratch[4][DIM];    // 2048 B (agg partials)
    __shared__ int   ni_lds[KN];         // 256 B
    // ~37.9 KB -> 4 blocks/CU

    const int b   = blockIdx.x;
    const int m   = blockIdx.y;
    const int tid = threadIdx.x;
    const int len = neigh_len[b];
    const int nd  = node_idx[b];
    const float* __restrict__ emb = m ? emb_t : emb_v;

    // ---- pre-phase: u row + passthrough (+ len==0 fallback); ni ----
    if (tid < DIM) {
        float uv = emb[(size_t)nd * DIM + tid];
        out[((size_t)m * NB + b) * DIM + tid] = uv;
        if (len == 0)
            out[((size_t)(2 + m) * NB + b) * DIM + tid] = uv;
        u_lds[tid] = uv;
    } else if (tid < DIM + KN) {
        ni_lds[tid - DIM] = neigh_idx[b * KN + (tid - DIM)];
    }
    if (len == 0) return;   // block-uniform
    __syncthreads();   // B0: u_lds, ni ready

    const int kt = tid >> 6;          // wave id == k-tile id
    const int l  = tid & 63;
    const int ll = tid & 15;
    const int lh = (tid >> 4) & 3;
    const int nkt = (len + 15) >> 4;  // 1..4, block-uniform

    // ---- per-wave gather of own 16 rows; uq partials overlap the latency ----
    if (kt < nkt) {
        #pragma unroll
        for (int it = 0; it < 4; ++it) {
            int r = kt * 16 + it * 4 + (l >> 4);
            bf16x8 v;
            if (r < len) {
                const float* src = emb + (size_t)ni_lds[r] * DIM + ll * 8;
                float4 f0 = ((const float4*)src)[0];
                float4 f1 = ((const float4*)src)[1];
                v[0] = (bf16)f0.x; v[1] = (bf16)f0.y; v[2] = (bf16)f0.z; v[3] = (bf16)f0.w;
                v[4] = (bf16)f1.x; v[5] = (bf16)f1.y; v[6] = (bf16)f1.z; v[7] = (bf16)f1.w;
            } else {
                #pragma unroll
                for (int q = 0; q < 8; ++q) v[q] = (bf16)0.f;
            }
            *(bf16x8*)&n_lds[r][ll * 8] = v;
        }
    }
    {
        // uq partial: part[h][j] = sum_{i in h-half} u[i] * w1[128+i][j]
        int j = tid & 127, h = tid >> 7;
        const bf16* wb = w1T + (size_t)j * 256 + DIM + h * 64;
        const float* us = &u_lds[h * 64];
        float a = 0.f;
        #pragma unroll
        for (int i = 0; i < 64; i += 8) {
            bf16x8 w = *(const bf16x8*)(wb + i);
            #pragma unroll
            for (int q = 0; q < 8; ++q) a = fmaf(us[i + q], (float)w[q], a);
        }
        part_lds[h][j] = a;
    }
    __syncthreads();   // B1: n_lds + uq partials ready — LAST barrier before scores

    if (kt < nkt) {
        // ======= GEMM1 (ks-outer, jt-inner): H1^T = W1top^T @ N^T =======
        f32x4 acc[8];
        #pragma unroll
        for (int jt = 0; jt < 8; ++jt) { f32x4 z = {0.f, 0.f, 0.f, 0.f}; acc[jt] = z; }
        #pragma unroll
        for (int ks = 0; ks < 4; ++ks) {
            bf16x8 bfr = *(const bf16x8*)&n_lds[kt * 16 + ll][ks * 32 + lh * 8];
            #pragma unroll
            for (int jt = 0; jt < 8; ++jt) {
                bf16x8 af = *(const bf16x8*)(w1T + (size_t)(jt * 16 + ll) * 256 + ks * 32 + lh * 8);
                acc[jt] = __builtin_amdgcn_mfma_f32_16x16x32_bf16(af, bfr, acc[jt], 0, 0, 0);
            }
        }
        // epilogue: +uq+b1, relu, pack to own h1 slice (wave-private: no barrier)
        #pragma unroll
        for (int jt = 0; jt < 8; ++jt) {
            float4 p0 = *(const float4*)&part_lds[0][jt * 16 + lh * 4];
            float4 p1 = *(const float4*)&part_lds[1][jt * 16 + lh * 4];
            float4 bq = *(const float4*)(b1 + jt * 16 + lh * 4);
            bf16x4 hv;
            hv[0] = (bf16)fmaxf(acc[jt][0] + p0.x + p1.x + bq.x, 0.f);
            hv[1] = (bf16)fmaxf(acc[jt][1] + p0.y + p1.y + bq.y, 0.f);
            hv[2] = (bf16)fmaxf(acc[jt][2] + p0.z + p1.z + bq.z, 0.f);
            hv[3] = (bf16)fmaxf(acc[jt][3] + p0.w + p1.w + bq.w, 0.f);
            *(bf16x4*)&h1_lds[kt * 16 + ll][jt * 16 + lh * 4] = hv;
        }

        // ======= GEMM2 (ks-outer, jt-inner): bias-in-init, relu+score =======
        f32x4 c[8];
        #pragma unroll
        for (int jt = 0; jt < 8; ++jt) {
            float4 bq = *(const float4*)(b2 + jt * 16 + lh * 4);
            f32x4 ci = {bq.x, bq.y, bq.z, bq.w};
            c[jt] = ci;
        }
        #pragma unroll
        for (int ks = 0; ks < 4; ++ks) {
            bf16x8 bfr = *(const bf16x8*)&h1_lds[kt * 16 + ll][ks * 32 + lh * 8];
            #pragma unroll
            for (int jt = 0; jt < 8; ++jt) {
                bf16x8 af = *(const bf16x8*)(w2T + (size_t)(jt * 16 + ll) * 128 + ks * 32 + lh * 8);
                c[jt] = __builtin_amdgcn_mfma_f32_16x16x32_bf16(af, bfr, c[jt], 0, 0, 0);
            }
        }
        float s = 0.f;
        #pragma unroll
        for (int jt = 0; jt < 8; ++jt) {
            float4 w3q = *(const float4*)(w3 + jt * 16 + lh * 4);
            s = fmaf(fmaxf(c[jt][0], 0.f), w3q.x, s);
            s = fmaf(fmaxf(c[jt][1], 0.f), w3q.y, s);
            s = fmaf(fmaxf(c[jt][2], 0.f), w3q.z, s);
            s = fmaf(fmaxf(c[jt][3], 0.f), w3q.w, s);
        }
        s += __shfl_xor(s, 16);
        s += __shfl_xor(s, 32);
        if (lh == 0) s_lds[kt * 16 + ll] = s;
    }
    __syncthreads();   // B2: scores ready

    // ---- softmax: all-wave redundant, in-register (lane l = neighbor k) ----
    float sv = (l < len) ? s_lds[l] : -1e30f;
    float mx = sv;
    #pragma unroll
    for (int off = 1; off < 64; off <<= 1) mx = fmaxf(mx, __shfl_xor(mx, off));
    float e = (l < len) ? __expf(sv - mx) : 0.f;
    float sum = e;
    #pragma unroll
    for (int off = 1; off < 64; off <<= 1) sum += __shfl_xor(sum, off);
    float attv = e / sum;

    // ---- aggregate own 16 rows; att broadcast by shfl ----
    {
        int slice = l >> 5;           // 0..1 (8 rows each)
        int j0 = (l & 31) * 4;
        float ax = 0.f, ay = 0.f, az = 0.f, aw = 0.f;
        if (kt < nkt) {
            #pragma unroll
            for (int q = 0; q < 8; ++q) {
                int k = kt * 16 + slice * 8 + q;
                float ak = __shfl(attv, k);
                bf16x4 nv = *(const bf16x4*)&n_lds[k][j0];
                ax = fmaf(ak, (float)nv[0], ax);
                ay = fmaf(ak, (float)nv[1], ay);
                az = fmaf(ak, (float)nv[2], az);
                aw = fmaf(ak, (float)nv[3], aw);
            }
        }
        ax += __shfl_xor(ax, 32);
        ay += __shfl_xor(ay, 32);
        az += __shfl_xor(az, 32);
        aw += __shfl_xor(aw, 32);
        if (l < 32) {
            float4 v4 = {ax, ay, az, aw};
            *(float4*)&scratch[kt][j0] = v4;   // skipped waves write zeros
        }
    }
    __syncthreads();   // B3: agg partials ready

    if (tid < 32) {
        float4 a0 = *(const float4*)&scratch[0][tid * 4];
        float4 a1 = *(const float4*)&scratch[1][tid * 4];
        float4 a2 = *(const float4*)&scratch[2][tid * 4];
        float4 a3 = *(const float4*)&scratch[3][tid * 4];
        float4 o = {a0.x + a1.x + a2.x + a3.x,
                    a0.y + a1.y + a2.y + a3.y,
                    a0.z + a1.z + a2.z + a3.z,
                    a0.w + a1.w + a2.w + a3.w};
        *(float4*)(out + ((size_t)(2 + m) * NB + b) * DIM + tid * 4) = o;
    }
}

extern "C" void kernel_launch(void* const* d_in, const int* in_sizes, int n_in,
                              void* d_out, int out_size, void* d_ws, size_t ws_size,
                              hipStream_t stream) {
    const int*   node_idx  = (const int*)d_in[0];
    const int*   neigh_idx = (const int*)d_in[1];
    const int*   neigh_len = (const int*)d_in[2];
    const float* emb_v     = (const float*)d_in[3];
    const float* emb_t     = (const float*)d_in[4];
    const float* w1        = (const float*)d_in[5];
    const float* b1        = (const float*)d_in[6];
    const float* w2        = (const float*)d_in[7];
    const float* b2        = (const float*)d_in[8];
    const float* w3        = (const float*)d_in[9];
    float* out = (float*)d_out;

    bf16* w1T = (bf16*)d_ws;                 // 128*256 bf16 = 64 KiB
    bf16* w2T = (bf16*)d_ws + 128 * 256;     // 128*128 bf16 = 32 KiB

    hipLaunchKernelGGL(prep_weights, dim3(192), dim3(256), 0, stream, w1, w2, w1T, w2T);
    hipLaunchKernelGGL(graphsage_mfma, dim3(NB, 2), dim3(256), 0, stream,
                       node_idx, neigh_idx, neigh_len, emb_v, emb_t,
                       w1T, b1, w2T, b2, w3, out);
}